// Round 3
// baseline (148.198 us; speedup 1.0000x reference)
//
#include <hip/hip_runtime.h>
#include <hip/hip_bf16.h>

#define B_N    8192
#define Z_N    10
#define IN_D   512
#define OUT_D  512
#define R_N    8
#define M_N    3
#define ALPHA  0.04419417382415922f   // 1/sqrt(512), SCALING=1 folded

// ---- grouped-GEMM geometry ----
#define NPC      16                    // nodes per chunk
#define BN       48                    // NPC * 3 columns
#define MAXCH    (B_N / NPC + Z_N)     // 522 worst-case chunks
#define BSTRIDE  1040                  // bytes per B_s column: 512*2 + 16 pad

// ---- ws layout (bytes) ----
#define OFF_WBF  0u
#define SZ_WBF   (Z_N * OUT_D * IN_D * 2u)        // 5,242,880
#define OFF_PERM (OFF_WBF + SZ_WBF)
#define SZ_PERM  (B_N * 4u)
#define OFF_ZARR (OFF_PERM + SZ_PERM)
#define SZ_ZARR  (B_N * 4u)
#define OFF_META (OFF_ZARR + SZ_ZARR)
#define SZ_META  ((1u + 3u * MAXCH) * 4u)
#define OFF_HIST (OFF_META + SZ_META)
#define SZ_HIST  (Z_N * 4u)
#define OFF_OFFS (OFF_HIST + SZ_HIST)
#define SZ_OFFS  (Z_N * 4u)
#define WS_NEED  (OFF_OFFS + SZ_OFFS)

#define MERGE_BLOCKS (Z_N * OUT_D / 2)  // 2560 (2 W-rows per block)
#define ZHIST_BLOCKS (B_N / 256)        // 32

typedef __attribute__((ext_vector_type(8))) short short8v;
typedef __attribute__((ext_vector_type(4))) float float4v;

__device__ __forceinline__ unsigned short f2bf(float f) {
    unsigned int x = __float_as_uint(f);
    x += 0x7fffu + ((x >> 16) & 1u);
    return (unsigned short)(x >> 16);
}
__device__ __forceinline__ float bfbits_lo(unsigned int u) { return __uint_as_float(u << 16); }
__device__ __forceinline__ float bfbits_hi(unsigned int u) { return __uint_as_float(u & 0xffff0000u); }

// ---------------------------------------------------------------------------
// K1: fused  (a) W-merge -> bf16   (b) z-extraction + global histogram
// ---------------------------------------------------------------------------
__global__ __launch_bounds__(256) void prep_kernel(
    const float* __restrict__ weights, const float* __restrict__ lora_A,
    const float* __restrict__ lora_B, const float* __restrict__ attrs,
    unsigned short* __restrict__ Wbf, int* __restrict__ zarr,
    int* __restrict__ hist) {
    int bid = blockIdx.x;
    int tid = threadIdx.x;
    if (bid < MERGE_BLOCKS) {
        int r = bid * 2 + (tid >> 7);          // global (z,o) row in [0, Z_N*OUT_D)
        int z = r >> 9;
        int q = tid & 127;                     // float4 index within row
        float lb[R_N];
        const float* bp = lora_B + (size_t)r * R_N;
#pragma unroll
        for (int rr = 0; rr < R_N; ++rr) lb[rr] = bp[rr] * ALPHA;

        const float4* w4 = reinterpret_cast<const float4*>(weights) + (size_t)r * 128 + q;
        const float4* a4 = reinterpret_cast<const float4*>(lora_A) + (size_t)z * (R_N * 128);
        float4 wv = *w4;
        float ax = wv.x * ALPHA, ay = wv.y * ALPHA;
        float az = wv.z * ALPHA, aw = wv.w * ALPHA;
#pragma unroll
        for (int rr = 0; rr < R_N; ++rr) {
            float4 av = a4[rr * 128 + q];
            ax += av.x * lb[rr]; ay += av.y * lb[rr];
            az += av.z * lb[rr]; aw += av.w * lb[rr];
        }
        ushort4 o;
        o.x = f2bf(ax); o.y = f2bf(ay); o.z = f2bf(az); o.w = f2bf(aw);
        *(reinterpret_cast<ushort4*>(Wbf + (size_t)r * IN_D) + q) = o;
    } else {
        __shared__ int h_s[Z_N];
        if (tid < Z_N) h_s[tid] = 0;
        __syncthreads();
        int n = (bid - MERGE_BLOCKS) * 256 + tid;   // exactly covers B_N
        const float* a = attrs + (size_t)n * Z_N;
        int z = 0;
#pragma unroll
        for (int zz = 1; zz < Z_N; ++zz)
            if (a[zz] > 0.5f) z = zz;
        zarr[n] = z;
        atomicAdd(&h_s[z], 1);
        __syncthreads();
        if (tid < Z_N) atomicAdd(&hist[tid], h_s[tid]);
    }
}

// ---------------------------------------------------------------------------
// K2: chunk table from histogram (1 tiny block)
// meta: [0]=chunk_count; [1..]=z; [1+MAXCH..]=nstart; [1+2*MAXCH..]=nn
// ---------------------------------------------------------------------------
__global__ void chunk_kernel(const int* __restrict__ hist, int* __restrict__ meta,
                             int* __restrict__ offs) {
    if (threadIdx.x == 0) {
        int cum = 0, nc = 0;
        for (int z = 0; z < Z_N; ++z) {
            int c = hist[z];
            offs[z] = cum;
            for (int j = 0; j < c; j += NPC) {
                meta[1 + nc] = z;
                meta[1 + MAXCH + nc] = cum + j;
                meta[1 + 2 * MAXCH + nc] = (c - j < NPC) ? (c - j) : NPC;
                ++nc;
            }
            cum += c;
        }
        meta[0] = nc;
    }
}

// ---------------------------------------------------------------------------
// K3: scatter nodes into z-sorted perm (order within z irrelevant to output)
// ---------------------------------------------------------------------------
__global__ __launch_bounds__(256) void scatter_kernel(
    const int* __restrict__ zarr, int* __restrict__ offs, int* __restrict__ perm) {
    int n = blockIdx.x * 256 + threadIdx.x;
    int z = zarr[n];
    int pos = atomicAdd(&offs[z], 1);
    perm[pos] = n;
}

// ---------------------------------------------------------------------------
// K4: grouped GEMM. One block = one chunk (<=16 same-z nodes), 8 waves cover
// all 512 output rows (64 rows x 48 cols per wave = 4x3 mfma_16x16x32_bf16).
// B (t, transposed+bf16) staged in LDS for FULL K once; A fragments loaded
// straight from L2-resident Wbf (16 fully-consumed cache lines per load).
// Single barrier; no barriers in K-loop.
// ---------------------------------------------------------------------------
__global__ __launch_bounds__(512, 4) void gemm_kernel(
    const unsigned short* __restrict__ Wbf, const float* __restrict__ t,
    const int* __restrict__ perm, const int* __restrict__ meta,
    float* __restrict__ out) {
    // bijective XCD-aware swizzle over [0, MAXCH)
    int orig = blockIdx.x;
    const int qq = MAXCH >> 3, r8 = MAXCH & 7;
    int xcd = orig & 7, off = orig >> 3;
    int chunk = (xcd < r8 ? xcd * (qq + 1) : r8 * (qq + 1) + (xcd - r8) * qq) + off;
    if (chunk >= meta[0]) return;
    int z  = meta[1 + chunk];
    int ns = meta[1 + MAXCH + chunk];
    int nn = meta[1 + 2 * MAXCH + chunk];

    __shared__ __align__(16) char B_s[BN * BSTRIDE];
    __shared__ int col_ob[BN];

    int tid = threadIdx.x;

    // ---- stage B: fp32 t -> bf16, transposed to [col=(n,d)][k] ----
    {
        int n = tid >> 5, grp = tid & 31;       // node slot, k-16-group
        int node = (n < nn) ? perm[ns + n] : -1;
        float f[48];
        if (node >= 0) {
            const float4* tp = reinterpret_cast<const float4*>(
                t + (size_t)node * (IN_D * M_N)) + grp * 12;
#pragma unroll
            for (int j = 0; j < 12; ++j) {
                float4 v = tp[j];
                f[4 * j]     = v.x; f[4 * j + 1] = v.y;
                f[4 * j + 2] = v.z; f[4 * j + 3] = v.w;
            }
        } else {
#pragma unroll
            for (int j = 0; j < 48; ++j) f[j] = 0.f;
        }
#pragma unroll
        for (int d = 0; d < 3; ++d) {
#pragma unroll
            for (int j = 0; j < 2; ++j) {
                short8v v;
#pragma unroll
                for (int i = 0; i < 8; ++i)
                    v[i] = (short)f2bf(f[3 * (j * 8 + i) + d]);
                *reinterpret_cast<short8v*>(
                    B_s + (n * 3 + d) * BSTRIDE + (grp * 2 + j) * 16) = v;
            }
        }
        if (tid < BN) {
            int nl = tid / 3, d = tid - nl * 3;
            col_ob[tid] = (nl < nn) ? perm[ns + nl] * (OUT_D * M_N) + d : -1;
        }
    }
    __syncthreads();

    int lane = tid & 63, wid = tid >> 6;
    int lrow = lane & 15, g = lane >> 4;
    int wrow = wid * 64;

    const unsigned short* Wz = Wbf + (size_t)z * OUT_D * IN_D;
    const unsigned short* ap0 = Wz + (size_t)(wrow + lrow) * IN_D + g * 8;
    const char* bp0 = B_s + lrow * BSTRIDE + g * 16;

    float4v acc[4][3];
#pragma unroll
    for (int mi = 0; mi < 4; ++mi)
#pragma unroll
        for (int ni = 0; ni < 3; ++ni) acc[mi][ni] = (float4v){0.f, 0.f, 0.f, 0.f};

#pragma unroll 2
    for (int kt = 0; kt < 16; ++kt) {
        short8v a[4], b[3];
#pragma unroll
        for (int mi = 0; mi < 4; ++mi)
            a[mi] = *reinterpret_cast<const short8v*>(ap0 + (size_t)mi * 16 * IN_D + kt * 32);
#pragma unroll
        for (int ni = 0; ni < 3; ++ni)
            b[ni] = *reinterpret_cast<const short8v*>(bp0 + ni * 16 * BSTRIDE + kt * 64);
#pragma unroll
        for (int mi = 0; mi < 4; ++mi)
#pragma unroll
            for (int ni = 0; ni < 3; ++ni)
                acc[mi][ni] = __builtin_amdgcn_mfma_f32_16x16x32_bf16(
                    a[mi], b[ni], acc[mi][ni], 0, 0, 0);
    }

    // C/D layout: col = lane&15 (B col), row = g*4+e within fragment (m89)
    int base_row = wrow + g * 4;
#pragma unroll
    for (int ni = 0; ni < 3; ++ni) {
        int ob = col_ob[ni * 16 + lrow];
        if (ob < 0) continue;
#pragma unroll
        for (int mi = 0; mi < 4; ++mi) {
            int orow = base_row + mi * 16;
#pragma unroll
            for (int e = 0; e < 4; ++e)
                out[ob + (size_t)(orow + e) * M_N] = acc[mi][ni][e];
        }
    }
}

// ---------------------------------------------------------------------------
// Fallback kernels (round-1 path) if ws is too small
// ---------------------------------------------------------------------------
__global__ __launch_bounds__(256) void merge_w_kernel(
    const float* __restrict__ weights, const float* __restrict__ lora_A,
    const float* __restrict__ lora_B, unsigned short* __restrict__ Wbf) {
    int zo = blockIdx.x;
    int z = zo >> 9;
    int o = zo & (OUT_D - 1);
    int tid = threadIdx.x;
    float lb[R_N];
    const float* bp = lora_B + ((size_t)z * OUT_D + o) * R_N;
#pragma unroll
    for (int r = 0; r < R_N; ++r) lb[r] = bp[r];
    const float* ap = lora_A + (size_t)z * R_N * IN_D;
    const float* wp = weights + ((size_t)z * OUT_D + o) * IN_D;
    unsigned short* op = Wbf + ((size_t)z * OUT_D + o) * IN_D;
    for (int i = tid; i < IN_D; i += 256) {
        float acc = wp[i];
#pragma unroll
        for (int r = 0; r < R_N; ++r) acc += ap[r * IN_D + i] * lb[r];
        op[i] = f2bf(acc * ALPHA);
    }
}

__global__ __launch_bounds__(256) void apply_kernel(
    const float* __restrict__ t, const float* __restrict__ attrs,
    const unsigned short* __restrict__ Wbf, float* __restrict__ out) {
    int b = blockIdx.x;
    int tid = threadIdx.x;
    const float* ab = attrs + (size_t)b * Z_N;
    int z = 0;
#pragma unroll
    for (int zz = 1; zz < Z_N; ++zz)
        if (ab[zz] > 0.5f) z = zz;
    __shared__ __align__(16) float t_s[IN_D * M_N];
    const float* tb = t + (size_t)b * (IN_D * M_N);
    for (int k = tid; k < IN_D * M_N; k += 256) t_s[k] = tb[k];
    __syncthreads();
    const unsigned short* w0 = Wbf + ((size_t)z * OUT_D + tid) * IN_D;
    const unsigned short* w1 = w0 + 256 * IN_D;
    float acc0[M_N] = {0.f, 0.f, 0.f};
    float acc1[M_N] = {0.f, 0.f, 0.f};
    for (int c = 0; c < IN_D; c += 8) {
        uint4 u0 = *reinterpret_cast<const uint4*>(w0 + c);
        uint4 u1 = *reinterpret_cast<const uint4*>(w1 + c);
        float wf0[8], wf1[8];
        unsigned int a0[4] = {u0.x, u0.y, u0.z, u0.w};
        unsigned int a1[4] = {u1.x, u1.y, u1.z, u1.w};
#pragma unroll
        for (int q = 0; q < 4; ++q) {
            wf0[2 * q] = bfbits_lo(a0[q]); wf0[2 * q + 1] = bfbits_hi(a0[q]);
            wf1[2 * q] = bfbits_lo(a1[q]); wf1[2 * q + 1] = bfbits_hi(a1[q]);
        }
        float tf[24];
        const float4* tv = reinterpret_cast<const float4*>(t_s + c * M_N);
#pragma unroll
        for (int q = 0; q < 6; ++q) {
            float4 v = tv[q];
            tf[4 * q] = v.x; tf[4 * q + 1] = v.y; tf[4 * q + 2] = v.z; tf[4 * q + 3] = v.w;
        }
#pragma unroll
        for (int cc = 0; cc < 8; ++cc)
#pragma unroll
            for (int d = 0; d < M_N; ++d) {
                acc0[d] += wf0[cc] * tf[cc * M_N + d];
                acc1[d] += wf1[cc] * tf[cc * M_N + d];
            }
    }
    float* ob = out + (size_t)b * (OUT_D * M_N);
#pragma unroll
    for (int d = 0; d < M_N; ++d) ob[tid * M_N + d] = acc0[d];
#pragma unroll
    for (int d = 0; d < M_N; ++d) ob[(tid + 256) * M_N + d] = acc1[d];
}

extern "C" void kernel_launch(void* const* d_in, const int* in_sizes, int n_in,
                              void* d_out, int out_size, void* d_ws, size_t ws_size,
                              hipStream_t stream) {
    const float* t       = (const float*)d_in[0];
    const float* attrs   = (const float*)d_in[1];
    const float* weights = (const float*)d_in[2];
    const float* lora_A  = (const float*)d_in[3];
    const float* lora_B  = (const float*)d_in[4];
    float* out = (float*)d_out;
    char* ws = (char*)d_ws;

    if (ws_size >= WS_NEED) {
        unsigned short* Wbf = (unsigned short*)(ws + OFF_WBF);
        int* perm = (int*)(ws + OFF_PERM);
        int* zarr = (int*)(ws + OFF_ZARR);
        int* meta = (int*)(ws + OFF_META);
        int* hist = (int*)(ws + OFF_HIST);
        int* offs = (int*)(ws + OFF_OFFS);

        hipMemsetAsync(hist, 0, SZ_HIST, stream);
        prep_kernel<<<MERGE_BLOCKS + ZHIST_BLOCKS, 256, 0, stream>>>(
            weights, lora_A, lora_B, attrs, Wbf, zarr, hist);
        chunk_kernel<<<1, 64, 0, stream>>>(hist, meta, offs);
        scatter_kernel<<<ZHIST_BLOCKS, 256, 0, stream>>>(zarr, offs, perm);
        gemm_kernel<<<MAXCH, 512, 0, stream>>>(Wbf, t, perm, meta, out);
    } else if (ws_size >= SZ_WBF) {
        unsigned short* Wbf = (unsigned short*)(ws + OFF_WBF);
        merge_w_kernel<<<Z_N * OUT_D, 256, 0, stream>>>(weights, lora_A, lora_B, Wbf);
        apply_kernel<<<B_N, 256, 0, stream>>>(t, attrs, Wbf, out);
    }
}

// Round 4
// 132.114 us; speedup vs baseline: 1.1217x; 1.1217x over previous
//
#include <hip/hip_runtime.h>
#include <hip/hip_bf16.h>

#define B_N    8192
#define Z_N    10
#define IN_D   512
#define OUT_D  512
#define R_N    8
#define M_N    3
#define ALPHA  0.04419417382415922f   // 1/sqrt(512), SCALING=1 folded

// ---- grouped-GEMM geometry ----
#define NPC      16                    // nodes per chunk
#define BN       48                    // NPC * 3 columns
#define MAXCH    (B_N / NPC + Z_N)     // 522 worst-case chunks
#define BSTRIDE  1040                  // bytes per B_s column: 512*2 + 16 pad

// ---- ws layout (bytes) ----
#define OFF_WBF  0u
#define SZ_WBF   (Z_N * OUT_D * IN_D * 2u)        // 5,242,880
#define OFF_PERM (OFF_WBF + SZ_WBF)
#define SZ_PERM  (B_N * 4u)
#define OFF_ZARR (OFF_PERM + SZ_PERM)
#define SZ_ZARR  (B_N * 4u)
#define OFF_META (OFF_ZARR + SZ_ZARR)
#define SZ_META  ((1u + 3u * MAXCH) * 4u)
#define OFF_HIST (OFF_META + SZ_META)
#define SZ_HIST  (Z_N * 4u)
#define OFF_OFFS (OFF_HIST + SZ_HIST)
#define SZ_OFFS  (Z_N * 4u)
#define WS_NEED  (OFF_OFFS + SZ_OFFS)

#define MERGE_BLOCKS (Z_N * OUT_D / 2)  // 2560 (2 W-rows per block)
#define ZHIST_BLOCKS (B_N / 256)        // 32

typedef __attribute__((ext_vector_type(8))) short short8v;
typedef __attribute__((ext_vector_type(4))) float float4v;

__device__ __forceinline__ unsigned short f2bf(float f) {
    unsigned int x = __float_as_uint(f);
    x += 0x7fffu + ((x >> 16) & 1u);
    return (unsigned short)(x >> 16);
}
__device__ __forceinline__ float bfbits_lo(unsigned int u) { return __uint_as_float(u << 16); }
__device__ __forceinline__ float bfbits_hi(unsigned int u) { return __uint_as_float(u & 0xffff0000u); }

// ---------------------------------------------------------------------------
// K1: fused  (a) W-merge -> bf16   (b) z-extraction + global histogram
// ---------------------------------------------------------------------------
__global__ __launch_bounds__(256) void prep_kernel(
    const float* __restrict__ weights, const float* __restrict__ lora_A,
    const float* __restrict__ lora_B, const float* __restrict__ attrs,
    unsigned short* __restrict__ Wbf, int* __restrict__ zarr,
    int* __restrict__ hist) {
    int bid = blockIdx.x;
    int tid = threadIdx.x;
    if (bid < MERGE_BLOCKS) {
        int r = bid * 2 + (tid >> 7);          // global (z,o) row in [0, Z_N*OUT_D)
        int z = r >> 9;
        int q = tid & 127;                     // float4 index within row
        float lb[R_N];
        const float* bp = lora_B + (size_t)r * R_N;
#pragma unroll
        for (int rr = 0; rr < R_N; ++rr) lb[rr] = bp[rr] * ALPHA;

        const float4* w4 = reinterpret_cast<const float4*>(weights) + (size_t)r * 128 + q;
        const float4* a4 = reinterpret_cast<const float4*>(lora_A) + (size_t)z * (R_N * 128);
        float4 wv = *w4;
        float ax = wv.x * ALPHA, ay = wv.y * ALPHA;
        float az = wv.z * ALPHA, aw = wv.w * ALPHA;
#pragma unroll
        for (int rr = 0; rr < R_N; ++rr) {
            float4 av = a4[rr * 128 + q];
            ax += av.x * lb[rr]; ay += av.y * lb[rr];
            az += av.z * lb[rr]; aw += av.w * lb[rr];
        }
        ushort4 o;
        o.x = f2bf(ax); o.y = f2bf(ay); o.z = f2bf(az); o.w = f2bf(aw);
        *(reinterpret_cast<ushort4*>(Wbf + (size_t)r * IN_D) + q) = o;
    } else {
        __shared__ int h_s[Z_N];
        if (tid < Z_N) h_s[tid] = 0;
        __syncthreads();
        int n = (bid - MERGE_BLOCKS) * 256 + tid;   // exactly covers B_N
        const float* a = attrs + (size_t)n * Z_N;
        int z = 0;
#pragma unroll
        for (int zz = 1; zz < Z_N; ++zz)
            if (a[zz] > 0.5f) z = zz;
        zarr[n] = z;
        atomicAdd(&h_s[z], 1);
        __syncthreads();
        if (tid < Z_N) atomicAdd(&hist[tid], h_s[tid]);
    }
}

// ---------------------------------------------------------------------------
// K2: chunk table from histogram — parallel (512 threads, redundant scan of
// the 10-entry histogram; each thread fills its share of the <=522 entries).
// meta: [0]=chunk_count; [1..]=z; [1+MAXCH..]=nstart; [1+2*MAXCH..]=nn
// ---------------------------------------------------------------------------
__global__ __launch_bounds__(512) void chunk_kernel(
    const int* __restrict__ hist, int* __restrict__ meta, int* __restrict__ offs) {
    int tid = threadIdx.x;
    int h[Z_N], nodebase[Z_N], chunkbase[Z_N + 1];
    int cum = 0, cc = 0;
#pragma unroll
    for (int z = 0; z < Z_N; ++z) {
        h[z] = hist[z];
        nodebase[z] = cum;
        chunkbase[z] = cc;
        cum += h[z];
        cc += (h[z] + NPC - 1) / NPC;
    }
    chunkbase[Z_N] = cc;
    if (tid == 0) meta[0] = cc;
    if (tid < Z_N) offs[tid] = nodebase[tid];
    for (int c = tid; c < cc; c += 512) {
        int z = 0;
#pragma unroll
        for (int zz = 0; zz < Z_N - 1; ++zz)
            if (c >= chunkbase[zz + 1]) z = zz + 1;
        int j = (c - chunkbase[z]) * NPC;
        meta[1 + c] = z;
        meta[1 + MAXCH + c] = nodebase[z] + j;
        int rem = h[z] - j;
        meta[1 + 2 * MAXCH + c] = rem < NPC ? rem : NPC;
    }
}

// ---------------------------------------------------------------------------
// K3: scatter nodes into z-sorted perm (order within z irrelevant to output)
// ---------------------------------------------------------------------------
__global__ __launch_bounds__(256) void scatter_kernel(
    const int* __restrict__ zarr, int* __restrict__ offs, int* __restrict__ perm) {
    int n = blockIdx.x * 256 + threadIdx.x;
    int z = zarr[n];
    int pos = atomicAdd(&offs[z], 1);
    perm[pos] = n;
}

// ---------------------------------------------------------------------------
// K4: grouped GEMM. One block = one chunk (<=16 same-z nodes), 8 waves cover
// all 512 output rows (64 rows x 48 cols per wave = 4x3 mfma_16x16x32_bf16).
// B (t, transposed+bf16) staged in LDS for FULL K once (single barrier).
// A fragments stream from L2-resident Wbf with explicit 2-deep register
// prefetch (fully unrolled K-loop -> all buffer indices static).
// ---------------------------------------------------------------------------
__global__ __launch_bounds__(512, 4) void gemm_kernel(
    const unsigned short* __restrict__ Wbf, const float* __restrict__ t,
    const int* __restrict__ perm, const int* __restrict__ meta,
    float* __restrict__ out) {
    // bijective XCD-aware swizzle over [0, MAXCH)
    int orig = blockIdx.x;
    const int qq = MAXCH >> 3, r8 = MAXCH & 7;
    int xcd = orig & 7, off = orig >> 3;
    int chunk = (xcd < r8 ? xcd * (qq + 1) : r8 * (qq + 1) + (xcd - r8) * qq) + off;
    if (chunk >= meta[0]) return;
    int z  = meta[1 + chunk];
    int ns = meta[1 + MAXCH + chunk];
    int nn = meta[1 + 2 * MAXCH + chunk];

    __shared__ __align__(16) char B_s[BN * BSTRIDE];
    __shared__ int col_ob[BN];

    int tid = threadIdx.x;
    int lane = tid & 63, wid = tid >> 6;
    int lrow = lane & 15, g = lane >> 4;
    int wrow = wid * 64;

    const unsigned short* Wz = Wbf + (size_t)z * OUT_D * IN_D;
    const unsigned short* ap0 = Wz + (size_t)(wrow + lrow) * IN_D + g * 8;
    const char* bp0 = B_s + lrow * BSTRIDE + g * 16;

    // ---- issue A prefetch for kt=0,1 BEFORE staging (hides under staging) ----
    short8v apf0[4], apf1[4];
#pragma unroll
    for (int mi = 0; mi < 4; ++mi) {
        apf0[mi] = *reinterpret_cast<const short8v*>(ap0 + (size_t)mi * 16 * IN_D);
        apf1[mi] = *reinterpret_cast<const short8v*>(ap0 + (size_t)mi * 16 * IN_D + 32);
    }

    // ---- stage B: fp32 t -> bf16, transposed to [col=(n,d)][k] ----
    {
        int n = tid >> 5, grp = tid & 31;       // node slot, k-16-group
        int node = (n < nn) ? perm[ns + n] : -1;
        float f[48];
        if (node >= 0) {
            const float4* tp = reinterpret_cast<const float4*>(
                t + (size_t)node * (IN_D * M_N)) + grp * 12;
#pragma unroll
            for (int j = 0; j < 12; ++j) {
                float4 v = tp[j];
                f[4 * j]     = v.x; f[4 * j + 1] = v.y;
                f[4 * j + 2] = v.z; f[4 * j + 3] = v.w;
            }
        } else {
#pragma unroll
            for (int j = 0; j < 48; ++j) f[j] = 0.f;
        }
#pragma unroll
        for (int d = 0; d < 3; ++d) {
#pragma unroll
            for (int j = 0; j < 2; ++j) {
                short8v v;
#pragma unroll
                for (int i = 0; i < 8; ++i)
                    v[i] = (short)f2bf(f[3 * (j * 8 + i) + d]);
                *reinterpret_cast<short8v*>(
                    B_s + (n * 3 + d) * BSTRIDE + (grp * 2 + j) * 16) = v;
            }
        }
        if (tid < BN) {
            int nl = tid / 3, d = tid - nl * 3;
            col_ob[tid] = (nl < nn) ? perm[ns + nl] * (OUT_D * M_N) + d : -1;
        }
    }
    __syncthreads();

    float4v acc[4][3];
#pragma unroll
    for (int mi = 0; mi < 4; ++mi)
#pragma unroll
        for (int ni = 0; ni < 3; ++ni) acc[mi][ni] = (float4v){0.f, 0.f, 0.f, 0.f};

    // one K-step: consume BUF (A frags for step KT), prefetch KT+2 into BUF
#define GSTEP(KT, BUF)                                                         \
    {                                                                          \
        short8v b0 = *reinterpret_cast<const short8v*>(bp0 + 0 * 16 * BSTRIDE + (KT) * 64); \
        short8v b1 = *reinterpret_cast<const short8v*>(bp0 + 1 * 16 * BSTRIDE + (KT) * 64); \
        short8v b2 = *reinterpret_cast<const short8v*>(bp0 + 2 * 16 * BSTRIDE + (KT) * 64); \
        short8v av[4];                                                         \
        _Pragma("unroll")                                                      \
        for (int mi = 0; mi < 4; ++mi) av[mi] = BUF[mi];                       \
        if ((KT) + 2 < 16) {                                                   \
            _Pragma("unroll")                                                  \
            for (int mi = 0; mi < 4; ++mi)                                     \
                BUF[mi] = *reinterpret_cast<const short8v*>(                   \
                    ap0 + (size_t)mi * 16 * IN_D + ((KT) + 2) * 32);           \
        }                                                                      \
        _Pragma("unroll")                                                      \
        for (int mi = 0; mi < 4; ++mi) {                                       \
            acc[mi][0] = __builtin_amdgcn_mfma_f32_16x16x32_bf16(av[mi], b0, acc[mi][0], 0, 0, 0); \
            acc[mi][1] = __builtin_amdgcn_mfma_f32_16x16x32_bf16(av[mi], b1, acc[mi][1], 0, 0, 0); \
            acc[mi][2] = __builtin_amdgcn_mfma_f32_16x16x32_bf16(av[mi], b2, acc[mi][2], 0, 0, 0); \
        }                                                                      \
    }

#pragma unroll
    for (int kp = 0; kp < 8; ++kp) {
        GSTEP(2 * kp, apf0);
        GSTEP(2 * kp + 1, apf1);
    }
#undef GSTEP

    // C/D layout: col = lane&15 (B col), row = g*4+e within fragment (m89)
    int base_row = wrow + g * 4;
#pragma unroll
    for (int ni = 0; ni < 3; ++ni) {
        int ob = col_ob[ni * 16 + lrow];
        if (ob < 0) continue;
#pragma unroll
        for (int mi = 0; mi < 4; ++mi) {
            int orow = base_row + mi * 16;
#pragma unroll
            for (int e = 0; e < 4; ++e)
                out[ob + (size_t)(orow + e) * M_N] = acc[mi][ni][e];
        }
    }
}

// ---------------------------------------------------------------------------
// Fallback kernels (round-1 path) if ws is too small
// ---------------------------------------------------------------------------
__global__ __launch_bounds__(256) void merge_w_kernel(
    const float* __restrict__ weights, const float* __restrict__ lora_A,
    const float* __restrict__ lora_B, unsigned short* __restrict__ Wbf) {
    int zo = blockIdx.x;
    int z = zo >> 9;
    int o = zo & (OUT_D - 1);
    int tid = threadIdx.x;
    float lb[R_N];
    const float* bp = lora_B + ((size_t)z * OUT_D + o) * R_N;
#pragma unroll
    for (int r = 0; r < R_N; ++r) lb[r] = bp[r];
    const float* ap = lora_A + (size_t)z * R_N * IN_D;
    const float* wp = weights + ((size_t)z * OUT_D + o) * IN_D;
    unsigned short* op = Wbf + ((size_t)z * OUT_D + o) * IN_D;
    for (int i = tid; i < IN_D; i += 256) {
        float acc = wp[i];
#pragma unroll
        for (int r = 0; r < R_N; ++r) acc += ap[r * IN_D + i] * lb[r];
        op[i] = f2bf(acc * ALPHA);
    }
}

__global__ __launch_bounds__(256) void apply_kernel(
    const float* __restrict__ t, const float* __restrict__ attrs,
    const unsigned short* __restrict__ Wbf, float* __restrict__ out) {
    int b = blockIdx.x;
    int tid = threadIdx.x;
    const float* ab = attrs + (size_t)b * Z_N;
    int z = 0;
#pragma unroll
    for (int zz = 1; zz < Z_N; ++zz)
        if (ab[zz] > 0.5f) z = zz;
    __shared__ __align__(16) float t_s[IN_D * M_N];
    const float* tb = t + (size_t)b * (IN_D * M_N);
    for (int k = tid; k < IN_D * M_N; k += 256) t_s[k] = tb[k];
    __syncthreads();
    const unsigned short* w0 = Wbf + ((size_t)z * OUT_D + tid) * IN_D;
    const unsigned short* w1 = w0 + 256 * IN_D;
    float acc0[M_N] = {0.f, 0.f, 0.f};
    float acc1[M_N] = {0.f, 0.f, 0.f};
    for (int c = 0; c < IN_D; c += 8) {
        uint4 u0 = *reinterpret_cast<const uint4*>(w0 + c);
        uint4 u1 = *reinterpret_cast<const uint4*>(w1 + c);
        float wf0[8], wf1[8];
        unsigned int a0[4] = {u0.x, u0.y, u0.z, u0.w};
        unsigned int a1[4] = {u1.x, u1.y, u1.z, u1.w};
#pragma unroll
        for (int q = 0; q < 4; ++q) {
            wf0[2 * q] = bfbits_lo(a0[q]); wf0[2 * q + 1] = bfbits_hi(a0[q]);
            wf1[2 * q] = bfbits_lo(a1[q]); wf1[2 * q + 1] = bfbits_hi(a1[q]);
        }
        float tf[24];
        const float4* tv = reinterpret_cast<const float4*>(t_s + c * M_N);
#pragma unroll
        for (int q = 0; q < 6; ++q) {
            float4 v = tv[q];
            tf[4 * q] = v.x; tf[4 * q + 1] = v.y; tf[4 * q + 2] = v.z; tf[4 * q + 3] = v.w;
        }
#pragma unroll
        for (int cc = 0; cc < 8; ++cc)
#pragma unroll
            for (int d = 0; d < M_N; ++d) {
                acc0[d] += wf0[cc] * tf[cc * M_N + d];
                acc1[d] += wf1[cc] * tf[cc * M_N + d];
            }
    }
    float* ob = out + (size_t)b * (OUT_D * M_N);
#pragma unroll
    for (int d = 0; d < M_N; ++d) ob[tid * M_N + d] = acc0[d];
#pragma unroll
    for (int d = 0; d < M_N; ++d) ob[(tid + 256) * M_N + d] = acc1[d];
}

extern "C" void kernel_launch(void* const* d_in, const int* in_sizes, int n_in,
                              void* d_out, int out_size, void* d_ws, size_t ws_size,
                              hipStream_t stream) {
    const float* t       = (const float*)d_in[0];
    const float* attrs   = (const float*)d_in[1];
    const float* weights = (const float*)d_in[2];
    const float* lora_A  = (const float*)d_in[3];
    const float* lora_B  = (const float*)d_in[4];
    float* out = (float*)d_out;
    char* ws = (char*)d_ws;

    if (ws_size >= WS_NEED) {
        unsigned short* Wbf = (unsigned short*)(ws + OFF_WBF);
        int* perm = (int*)(ws + OFF_PERM);
        int* zarr = (int*)(ws + OFF_ZARR);
        int* meta = (int*)(ws + OFF_META);
        int* hist = (int*)(ws + OFF_HIST);
        int* offs = (int*)(ws + OFF_OFFS);

        hipMemsetAsync(hist, 0, SZ_HIST, stream);
        prep_kernel<<<MERGE_BLOCKS + ZHIST_BLOCKS, 256, 0, stream>>>(
            weights, lora_A, lora_B, attrs, Wbf, zarr, hist);
        chunk_kernel<<<1, 512, 0, stream>>>(hist, meta, offs);
        scatter_kernel<<<ZHIST_BLOCKS, 256, 0, stream>>>(zarr, offs, perm);
        gemm_kernel<<<MAXCH, 512, 0, stream>>>(Wbf, t, perm, meta, out);
    } else if (ws_size >= SZ_WBF) {
        unsigned short* Wbf = (unsigned short*)(ws + OFF_WBF);
        merge_w_kernel<<<Z_N * OUT_D, 256, 0, stream>>>(weights, lora_A, lora_B, Wbf);
        apply_kernel<<<B_N, 256, 0, stream>>>(t, attrs, Wbf, out);
    }
}

// Round 5
// 112.553 us; speedup vs baseline: 1.3167x; 1.1738x over previous
//
#include <hip/hip_runtime.h>
#include <hip/hip_bf16.h>

#define B_N    8192
#define Z_N    10
#define IN_D   512
#define OUT_D  512
#define R_N    8
#define M_N    3
#define ALPHA  0.04419417382415922f   // 1/sqrt(512), SCALING=1 folded

// ---- grouped-GEMM geometry ----
#define NPC      16                    // nodes per chunk
#define BN       48                    // NPC * 3 columns
#define MAXCH    (B_N / NPC + Z_N)     // 522 worst-case chunks
#define BSTRIDE  1040                  // bytes per B_s column: 512*2 + 16 pad

// ---- ws layout (bytes) ----
#define OFF_WBF  0u
#define SZ_WBF   (Z_N * OUT_D * IN_D * 2u)        // 5,242,880
#define OFF_PERM (OFF_WBF + SZ_WBF)
#define SZ_PERM  (B_N * 4u)
#define OFF_ZARR (OFF_PERM + SZ_PERM)
#define SZ_ZARR  (B_N * 4u)
#define OFF_HIST (OFF_ZARR + SZ_ZARR)
#define SZ_HIST  (Z_N * 4u)
#define OFF_CNT  (OFF_HIST + SZ_HIST)
#define SZ_CNT   (Z_N * 4u)
#define WS_NEED  (OFF_CNT + SZ_CNT)

#define MERGE_BLOCKS (Z_N * OUT_D / 2)  // 2560 (2 W-rows per block)
#define ZHIST_BLOCKS (B_N / 256)        // 32

typedef __attribute__((ext_vector_type(8))) short short8v;
typedef __attribute__((ext_vector_type(4))) float float4v;

__device__ __forceinline__ unsigned short f2bf(float f) {
    unsigned int x = __float_as_uint(f);
    x += 0x7fffu + ((x >> 16) & 1u);
    return (unsigned short)(x >> 16);
}
__device__ __forceinline__ float bfbits_lo(unsigned int u) { return __uint_as_float(u << 16); }
__device__ __forceinline__ float bfbits_hi(unsigned int u) { return __uint_as_float(u & 0xffff0000u); }

// async global->LDS, 16B per lane; LDS dest is wave-uniform base + lane*16
__device__ __forceinline__ void gload_lds16(const void* g, void* l) {
    __builtin_amdgcn_global_load_lds(
        (const __attribute__((address_space(1))) void*)g,
        (__attribute__((address_space(3))) void*)l, 16, 0, 0);
}

// ---------------------------------------------------------------------------
// K1: fused  (a) W-merge -> bf16   (b) z-extraction + global histogram
// ---------------------------------------------------------------------------
__global__ __launch_bounds__(256) void prep_kernel(
    const float* __restrict__ weights, const float* __restrict__ lora_A,
    const float* __restrict__ lora_B, const float* __restrict__ attrs,
    unsigned short* __restrict__ Wbf, int* __restrict__ zarr,
    int* __restrict__ hist) {
    int bid = blockIdx.x;
    int tid = threadIdx.x;
    if (bid < MERGE_BLOCKS) {
        int r = bid * 2 + (tid >> 7);          // global (z,o) row in [0, Z_N*OUT_D)
        int z = r >> 9;
        int q = tid & 127;                     // float4 index within row
        float lb[R_N];
        const float* bp = lora_B + (size_t)r * R_N;
#pragma unroll
        for (int rr = 0; rr < R_N; ++rr) lb[rr] = bp[rr] * ALPHA;

        const float4* w4 = reinterpret_cast<const float4*>(weights) + (size_t)r * 128 + q;
        const float4* a4 = reinterpret_cast<const float4*>(lora_A) + (size_t)z * (R_N * 128);
        float4 wv = *w4;
        float ax = wv.x * ALPHA, ay = wv.y * ALPHA;
        float az = wv.z * ALPHA, aw = wv.w * ALPHA;
#pragma unroll
        for (int rr = 0; rr < R_N; ++rr) {
            float4 av = a4[rr * 128 + q];
            ax += av.x * lb[rr]; ay += av.y * lb[rr];
            az += av.z * lb[rr]; aw += av.w * lb[rr];
        }
        ushort4 o;
        o.x = f2bf(ax); o.y = f2bf(ay); o.z = f2bf(az); o.w = f2bf(aw);
        *(reinterpret_cast<ushort4*>(Wbf + (size_t)r * IN_D) + q) = o;
    } else {
        __shared__ int h_s[Z_N];
        if (tid < Z_N) h_s[tid] = 0;
        __syncthreads();
        int n = (bid - MERGE_BLOCKS) * 256 + tid;   // exactly covers B_N
        const float* a = attrs + (size_t)n * Z_N;
        int z = 0;
#pragma unroll
        for (int zz = 1; zz < Z_N; ++zz)
            if (a[zz] > 0.5f) z = zz;
        zarr[n] = z;
        atomicAdd(&h_s[z], 1);
        __syncthreads();
        if (tid < Z_N) atomicAdd(&hist[tid], h_s[tid]);
    }
}

// ---------------------------------------------------------------------------
// K2: scatter nodes into z-sorted perm (base from hist prefix + counters)
// ---------------------------------------------------------------------------
__global__ __launch_bounds__(256) void scatter_kernel(
    const int* __restrict__ zarr, const int* __restrict__ hist,
    int* __restrict__ cnt, int* __restrict__ perm) {
    int n = blockIdx.x * 256 + threadIdx.x;
    int z = zarr[n];
    int base = 0;
#pragma unroll
    for (int zz = 0; zz < Z_N; ++zz)
        base += (zz < z) ? hist[zz] : 0;
    int pos = base + atomicAdd(&cnt[z], 1);
    perm[pos] = n;
}

// ---------------------------------------------------------------------------
// K3: grouped GEMM. One block = one chunk (<=16 same-z nodes), 8 waves cover
// all 512 output rows (64 rows x 48 cols per wave = 4x3 mfma_16x16x32_bf16).
// B (t, transposed+bf16) staged in LDS for full K once (one barrier total).
// A staged via async global_load_lds into a 3-buffer (2-deep) pipeline,
// counted vmcnt, NO barriers in the K-loop: each wave stages and consumes
// only its own 64 rows.
// ---------------------------------------------------------------------------
__global__ __launch_bounds__(512, 2) void gemm_kernel(
    const unsigned short* __restrict__ Wbf, const float* __restrict__ t,
    const int* __restrict__ perm, const int* __restrict__ hist,
    float* __restrict__ out) {
    // bijective XCD-aware swizzle over [0, MAXCH)
    int orig = blockIdx.x;
    const int qq = MAXCH >> 3, r8 = MAXCH & 7;
    int xcd = orig & 7, off = orig >> 3;
    int chunk = (xcd < r8 ? xcd * (qq + 1) : r8 * (qq + 1) + (xcd - r8) * qq) + off;

    // chunk table recomputed from the 10-entry histogram (scalar, no arrays)
    int z = -1, ns = 0, nn = 0;
    {
        int cum = 0, cc = 0;
#pragma unroll
        for (int zz = 0; zz < Z_N; ++zz) {
            int hz = hist[zz];
            int czz = (hz + NPC - 1) / NPC;
            if (z < 0 && chunk < cc + czz) {
                z = zz;
                int j = (chunk - cc) * NPC;
                ns = cum + j;
                nn = (hz - j < NPC) ? (hz - j) : NPC;
            }
            cum += hz; cc += czz;
        }
        if (chunk >= cc) return;
    }

    __shared__ __align__(16) char A_s[3 * 32768];   // 3 x (512 rows x 32 cols bf16)
    __shared__ __align__(16) char B_s[BN * BSTRIDE];
    __shared__ int col_ob[BN];

    int tid = threadIdx.x;
    int lane = tid & 63, wid = tid >> 6;
    int lrow = lane & 15, g = lane >> 4;
    int wrow = wid * 64;

    const unsigned short* Wz = Wbf + (size_t)z * OUT_D * IN_D;

    // ---- stage B: fp32 t -> bf16, transposed to [col=(n,d)][k] ----
    {
        int n = tid >> 5, grp = tid & 31;       // node slot, k-16-group
        int node = (n < nn) ? perm[ns + n] : -1;
        float f[48];
        if (node >= 0) {
            const float4* tp = reinterpret_cast<const float4*>(
                t + (size_t)node * (IN_D * M_N)) + grp * 12;
#pragma unroll
            for (int j = 0; j < 12; ++j) {
                float4 v = tp[j];
                f[4 * j]     = v.x; f[4 * j + 1] = v.y;
                f[4 * j + 2] = v.z; f[4 * j + 3] = v.w;
            }
        } else {
#pragma unroll
            for (int j = 0; j < 48; ++j) f[j] = 0.f;
        }

        // ---- prologue A staging: kt=0 -> buf0, kt=1 -> buf1 (async, in flight
        //      under the B conversion + barrier) ----
        {
            char* ldst0 = A_s + 0 * 32768 + wid * 4096;
            char* ldst1 = A_s + 1 * 32768 + wid * 4096;
            const unsigned short* gs = Wz + (size_t)(wrow + (lane >> 2)) * IN_D
                                          + (lane & 3) * 8;
#pragma unroll
            for (int j = 0; j < 4; ++j)
                gload_lds16(gs + j * 16 * IN_D, ldst0 + j * 1024);
#pragma unroll
            for (int j = 0; j < 4; ++j)
                gload_lds16(gs + j * 16 * IN_D + 32, ldst1 + j * 1024);
        }

#pragma unroll
        for (int d = 0; d < 3; ++d) {
#pragma unroll
            for (int j = 0; j < 2; ++j) {
                short8v v;
#pragma unroll
                for (int i = 0; i < 8; ++i)
                    v[i] = (short)f2bf(f[3 * (j * 8 + i) + d]);
                *reinterpret_cast<short8v*>(
                    B_s + (n * 3 + d) * BSTRIDE + (grp * 2 + j) * 16) = v;
            }
        }
        if (tid < BN) {
            int nl = tid / 3, d = tid - nl * 3;
            col_ob[tid] = (nl < nn) ? perm[ns + nl] * (OUT_D * M_N) + d : -1;
        }
    }
    __syncthreads();

    float4v acc[4][3];
#pragma unroll
    for (int mi = 0; mi < 4; ++mi)
#pragma unroll
        for (int ni = 0; ni < 3; ++ni) acc[mi][ni] = (float4v){0.f, 0.f, 0.f, 0.f};

    const char* bp0 = B_s + lrow * BSTRIDE + g * 16;

// one K-step: issue async stage of kt+2 into buf (kt+2)%3, counted-vmcnt wait
// for buf kt%3 (8 = 2 buffers in flight), consume from LDS, 12 MFMAs.
#define KSTEP(KT)                                                               \
    {                                                                           \
        __builtin_amdgcn_sched_barrier(0);                                      \
        if ((KT) + 2 < 16) {                                                    \
            char* ldst = A_s + (((KT) + 2) % 3) * 32768 + wid * 4096;           \
            const unsigned short* gs = Wz + (size_t)(wrow + (lane >> 2)) * IN_D \
                                          + ((KT) + 2) * 32 + (lane & 3) * 8;   \
            gload_lds16(gs + 0 * 16 * IN_D, ldst + 0 * 1024);                   \
            gload_lds16(gs + 1 * 16 * IN_D, ldst + 1 * 1024);                   \
            gload_lds16(gs + 2 * 16 * IN_D, ldst + 2 * 1024);                   \
            gload_lds16(gs + 3 * 16 * IN_D, ldst + 3 * 1024);                   \
        }                                                                       \
        asm volatile("s_waitcnt vmcnt(%0)"                                      \
                     :: "n"(((KT) + 2 < 16) ? 8 : (((KT) + 1 < 16) ? 4 : 0))    \
                     : "memory");                                               \
        __builtin_amdgcn_sched_barrier(0);                                      \
        const char* ab = A_s + ((KT) % 3) * 32768 + wid * 4096                  \
                         + lrow * 64 + g * 16;                                  \
        short8v a0 = *reinterpret_cast<const short8v*>(ab + 0 * 1024);          \
        short8v a1 = *reinterpret_cast<const short8v*>(ab + 1 * 1024);          \
        short8v a2 = *reinterpret_cast<const short8v*>(ab + 2 * 1024);          \
        short8v a3 = *reinterpret_cast<const short8v*>(ab + 3 * 1024);          \
        short8v b0 = *reinterpret_cast<const short8v*>(bp0 + 0 * 16 * BSTRIDE + (KT) * 64); \
        short8v b1 = *reinterpret_cast<const short8v*>(bp0 + 1 * 16 * BSTRIDE + (KT) * 64); \
        short8v b2 = *reinterpret_cast<const short8v*>(bp0 + 2 * 16 * BSTRIDE + (KT) * 64); \
        __builtin_amdgcn_s_setprio(1);                                          \
        acc[0][0] = __builtin_amdgcn_mfma_f32_16x16x32_bf16(a0, b0, acc[0][0], 0, 0, 0); \
        acc[0][1] = __builtin_amdgcn_mfma_f32_16x16x32_bf16(a0, b1, acc[0][1], 0, 0, 0); \
        acc[0][2] = __builtin_amdgcn_mfma_f32_16x16x32_bf16(a0, b2, acc[0][2], 0, 0, 0); \
        acc[1][0] = __builtin_amdgcn_mfma_f32_16x16x32_bf16(a1, b0, acc[1][0], 0, 0, 0); \
        acc[1][1] = __builtin_amdgcn_mfma_f32_16x16x32_bf16(a1, b1, acc[1][1], 0, 0, 0); \
        acc[1][2] = __builtin_amdgcn_mfma_f32_16x16x32_bf16(a1, b2, acc[1][2], 0, 0, 0); \
        acc[2][0] = __builtin_amdgcn_mfma_f32_16x16x32_bf16(a2, b0, acc[2][0], 0, 0, 0); \
        acc[2][1] = __builtin_amdgcn_mfma_f32_16x16x32_bf16(a2, b1, acc[2][1], 0, 0, 0); \
        acc[2][2] = __builtin_amdgcn_mfma_f32_16x16x32_bf16(a2, b2, acc[2][2], 0, 0, 0); \
        acc[3][0] = __builtin_amdgcn_mfma_f32_16x16x32_bf16(a3, b0, acc[3][0], 0, 0, 0); \
        acc[3][1] = __builtin_amdgcn_mfma_f32_16x16x32_bf16(a3, b1, acc[3][1], 0, 0, 0); \
        acc[3][2] = __builtin_amdgcn_mfma_f32_16x16x32_bf16(a3, b2, acc[3][2], 0, 0, 0); \
        __builtin_amdgcn_s_setprio(0);                                          \
    }

    KSTEP(0)  KSTEP(1)  KSTEP(2)  KSTEP(3)
    KSTEP(4)  KSTEP(5)  KSTEP(6)  KSTEP(7)
    KSTEP(8)  KSTEP(9)  KSTEP(10) KSTEP(11)
    KSTEP(12) KSTEP(13) KSTEP(14) KSTEP(15)
#undef KSTEP

    // C/D layout: col = lane&15 (B col), row = g*4+e within fragment (m89)
    int base_row = wrow + g * 4;
#pragma unroll
    for (int ni = 0; ni < 3; ++ni) {
        int ob = col_ob[ni * 16 + lrow];
        if (ob < 0) continue;
#pragma unroll
        for (int mi = 0; mi < 4; ++mi) {
            int orow = base_row + mi * 16;
#pragma unroll
            for (int e = 0; e < 4; ++e)
                out[ob + (size_t)(orow + e) * M_N] = acc[mi][ni][e];
        }
    }
}

// ---------------------------------------------------------------------------
// Fallback (round-1 path) if ws is too small
// ---------------------------------------------------------------------------
__global__ __launch_bounds__(256) void merge_w_kernel(
    const float* __restrict__ weights, const float* __restrict__ lora_A,
    const float* __restrict__ lora_B, unsigned short* __restrict__ Wbf) {
    int zo = blockIdx.x;
    int z = zo >> 9;
    int o = zo & (OUT_D - 1);
    int tid = threadIdx.x;
    float lb[R_N];
    const float* bp = lora_B + ((size_t)z * OUT_D + o) * R_N;
#pragma unroll
    for (int r = 0; r < R_N; ++r) lb[r] = bp[r];
    const float* ap = lora_A + (size_t)z * R_N * IN_D;
    const float* wp = weights + ((size_t)z * OUT_D + o) * IN_D;
    unsigned short* op = Wbf + ((size_t)z * OUT_D + o) * IN_D;
    for (int i = tid; i < IN_D; i += 256) {
        float acc = wp[i];
#pragma unroll
        for (int r = 0; r < R_N; ++r) acc += ap[r * IN_D + i] * lb[r];
        op[i] = f2bf(acc * ALPHA);
    }
}

__global__ __launch_bounds__(256) void apply_kernel(
    const float* __restrict__ t, const float* __restrict__ attrs,
    const unsigned short* __restrict__ Wbf, float* __restrict__ out) {
    int b = blockIdx.x;
    int tid = threadIdx.x;
    const float* ab = attrs + (size_t)b * Z_N;
    int z = 0;
#pragma unroll
    for (int zz = 1; zz < Z_N; ++zz)
        if (ab[zz] > 0.5f) z = zz;
    __shared__ __align__(16) float t_s[IN_D * M_N];
    const float* tb = t + (size_t)b * (IN_D * M_N);
    for (int k = tid; k < IN_D * M_N; k += 256) t_s[k] = tb[k];
    __syncthreads();
    const unsigned short* w0 = Wbf + ((size_t)z * OUT_D + tid) * IN_D;
    const unsigned short* w1 = w0 + 256 * IN_D;
    float acc0[M_N] = {0.f, 0.f, 0.f};
    float acc1[M_N] = {0.f, 0.f, 0.f};
    for (int c = 0; c < IN_D; c += 8) {
        uint4 u0 = *reinterpret_cast<const uint4*>(w0 + c);
        uint4 u1 = *reinterpret_cast<const uint4*>(w1 + c);
        float wf0[8], wf1[8];
        unsigned int a0[4] = {u0.x, u0.y, u0.z, u0.w};
        unsigned int a1[4] = {u1.x, u1.y, u1.z, u1.w};
#pragma unroll
        for (int q = 0; q < 4; ++q) {
            wf0[2 * q] = bfbits_lo(a0[q]); wf0[2 * q + 1] = bfbits_hi(a0[q]);
            wf1[2 * q] = bfbits_lo(a1[q]); wf1[2 * q + 1] = bfbits_hi(a1[q]);
        }
        float tf[24];
        const float4* tv = reinterpret_cast<const float4*>(t_s + c * M_N);
#pragma unroll
        for (int q = 0; q < 6; ++q) {
            float4 v = tv[q];
            tf[4 * q] = v.x; tf[4 * q + 1] = v.y; tf[4 * q + 2] = v.z; tf[4 * q + 3] = v.w;
        }
#pragma unroll
        for (int cc = 0; cc < 8; ++cc)
#pragma unroll
            for (int d = 0; d < M_N; ++d) {
                acc0[d] += wf0[cc] * tf[cc * M_N + d];
                acc1[d] += wf1[cc] * tf[cc * M_N + d];
            }
    }
    float* ob = out + (size_t)b * (OUT_D * M_N);
#pragma unroll
    for (int d = 0; d < M_N; ++d) ob[tid * M_N + d] = acc0[d];
#pragma unroll
    for (int d = 0; d < M_N; ++d) ob[(tid + 256) * M_N + d] = acc1[d];
}

extern "C" void kernel_launch(void* const* d_in, const int* in_sizes, int n_in,
                              void* d_out, int out_size, void* d_ws, size_t ws_size,
                              hipStream_t stream) {
    const float* t       = (const float*)d_in[0];
    const float* attrs   = (const float*)d_in[1];
    const float* weights = (const float*)d_in[2];
    const float* lora_A  = (const float*)d_in[3];
    const float* lora_B  = (const float*)d_in[4];
    float* out = (float*)d_out;
    char* ws = (char*)d_ws;

    if (ws_size >= WS_NEED) {
        unsigned short* Wbf = (unsigned short*)(ws + OFF_WBF);
        int* perm = (int*)(ws + OFF_PERM);
        int* zarr = (int*)(ws + OFF_ZARR);
        int* hist = (int*)(ws + OFF_HIST);
        int* cnt  = (int*)(ws + OFF_CNT);

        hipMemsetAsync(hist, 0, SZ_HIST + SZ_CNT, stream);
        prep_kernel<<<MERGE_BLOCKS + ZHIST_BLOCKS, 256, 0, stream>>>(
            weights, lora_A, lora_B, attrs, Wbf, zarr, hist);
        scatter_kernel<<<ZHIST_BLOCKS, 256, 0, stream>>>(zarr, hist, cnt, perm);
        gemm_kernel<<<MAXCH, 512, 0, stream>>>(Wbf, t, perm, hist, out);
    } else if (ws_size >= SZ_WBF) {
        unsigned short* Wbf = (unsigned short*)(ws + OFF_WBF);
        merge_w_kernel<<<Z_N * OUT_D, 256, 0, stream>>>(weights, lora_A, lora_B, Wbf);
        apply_kernel<<<B_N, 256, 0, stream>>>(t, attrs, Wbf, out);
    }
}

// Round 6
// 106.473 us; speedup vs baseline: 1.3919x; 1.0571x over previous
//
#include <hip/hip_runtime.h>
#include <hip/hip_bf16.h>

#define B_N    8192
#define Z_N    10
#define IN_D   512
#define OUT_D  512
#define R_N    8
#define M_N    3
#define ALPHA  0.04419417382415922f   // 1/sqrt(512), SCALING=1 folded

// ---- grouped-GEMM geometry ----
#define NPC      16                    // nodes per chunk
#define BN       48                    // NPC * 3 columns
#define MAXCH    (B_N / NPC + Z_N)     // 522 worst-case chunks
#define BSTRIDE  1040                  // bytes per B_s column: 512*2 + 16 pad

// Wt tiled layout: [z][kt(16)][row(512)][32 ushorts = 64B covering k=kt*32..+31]
// byte(z,kt,row,k) = ((z*16+kt)*512 + row)*64 + ((k&31)>>3)*16 + (k&7)*2

// ---- ws layout (bytes) ----
#define OFF_WT   0u
#define SZ_WT    (Z_N * OUT_D * IN_D * 2u)        // 5,242,880
#define OFF_PERM (OFF_WT + SZ_WT)
#define SZ_PERM  (B_N * 4u)
#define OFF_ZARR (OFF_PERM + SZ_PERM)
#define SZ_ZARR  (B_N * 4u)
#define OFF_HIST (OFF_ZARR + SZ_ZARR)
#define SZ_HIST  (Z_N * 4u)
#define OFF_CNT  (OFF_HIST + SZ_HIST)
#define SZ_CNT   (Z_N * 4u)
#define WS_NEED  (OFF_CNT + SZ_CNT)

#define MERGE_BLOCKS (Z_N * OUT_D / 2)  // 2560 (2 W-rows per block)
#define ZHIST_BLOCKS (B_N / 256)        // 32

typedef __attribute__((ext_vector_type(8))) short short8v;
typedef __attribute__((ext_vector_type(4))) float float4v;

__device__ __forceinline__ unsigned short f2bf(float f) {
    unsigned int x = __float_as_uint(f);
    x += 0x7fffu + ((x >> 16) & 1u);
    return (unsigned short)(x >> 16);
}
__device__ __forceinline__ float bfbits_lo(unsigned int u) { return __uint_as_float(u << 16); }
__device__ __forceinline__ float bfbits_hi(unsigned int u) { return __uint_as_float(u & 0xffff0000u); }

// ---------------------------------------------------------------------------
// K1: fused  (a) W-merge -> bf16 in TILED Wt layout   (b) z-extract + hist
// ---------------------------------------------------------------------------
__global__ __launch_bounds__(256) void prep_kernel(
    const float* __restrict__ weights, const float* __restrict__ lora_A,
    const float* __restrict__ lora_B, const float* __restrict__ attrs,
    unsigned short* __restrict__ Wt, int* __restrict__ zarr,
    int* __restrict__ hist) {
    int bid = blockIdx.x;
    int tid = threadIdx.x;
    if (bid < MERGE_BLOCKS) {
        int r = bid * 2 + (tid >> 7);          // global (z,o) row in [0, Z_N*OUT_D)
        int z = r >> 9;
        int o = r & 511;
        int q = tid & 127;                     // float4 index within row (k0 = 4q)
        float lb[R_N];
        const float* bp = lora_B + (size_t)r * R_N;
#pragma unroll
        for (int rr = 0; rr < R_N; ++rr) lb[rr] = bp[rr] * ALPHA;

        const float4* w4 = reinterpret_cast<const float4*>(weights) + (size_t)r * 128 + q;
        const float4* a4 = reinterpret_cast<const float4*>(lora_A) + (size_t)z * (R_N * 128);
        float4 wv = *w4;
        float ax = wv.x * ALPHA, ay = wv.y * ALPHA;
        float az = wv.z * ALPHA, aw = wv.w * ALPHA;
#pragma unroll
        for (int rr = 0; rr < R_N; ++rr) {
            float4 av = a4[rr * 128 + q];
            ax += av.x * lb[rr]; ay += av.y * lb[rr];
            az += av.z * lb[rr]; aw += av.w * lb[rr];
        }
        ushort4 o4;
        o4.x = f2bf(ax); o4.y = f2bf(ay); o4.z = f2bf(az); o4.w = f2bf(aw);
        // tiled write: kt = q>>3, 8B slot (q&7) within the row's 64B line
        size_t byte = ((size_t)z * 8192 + (size_t)(q >> 3) * 512 + o) * 64
                      + (size_t)(q & 7) * 8;
        *reinterpret_cast<ushort4*>(reinterpret_cast<char*>(Wt) + byte) = o4;
    } else {
        __shared__ int h_s[Z_N];
        if (tid < Z_N) h_s[tid] = 0;
        __syncthreads();
        int n = (bid - MERGE_BLOCKS) * 256 + tid;   // exactly covers B_N
        const float* a = attrs + (size_t)n * Z_N;
        int z = 0;
#pragma unroll
        for (int zz = 1; zz < Z_N; ++zz)
            if (a[zz] > 0.5f) z = zz;
        zarr[n] = z;
        atomicAdd(&h_s[z], 1);
        __syncthreads();
        if (tid < Z_N) atomicAdd(&hist[tid], h_s[tid]);
    }
}

// ---------------------------------------------------------------------------
// K2: scatter nodes into z-sorted perm (base from hist prefix + counters)
// ---------------------------------------------------------------------------
__global__ __launch_bounds__(256) void scatter_kernel(
    const int* __restrict__ zarr, const int* __restrict__ hist,
    int* __restrict__ cnt, int* __restrict__ perm) {
    int n = blockIdx.x * 256 + threadIdx.x;
    int z = zarr[n];
    int base = 0;
#pragma unroll
    for (int zz = 0; zz < Z_N; ++zz)
        base += (zz < z) ? hist[zz] : 0;
    int pos = base + atomicAdd(&cnt[z], 1);
    perm[pos] = n;
}

// ---------------------------------------------------------------------------
// K3: grouped GEMM. One block = one chunk (<=16 same-z nodes), 8 waves cover
// all 512 output rows (64 rows x 48 cols per wave = 4x3 mfma_16x16x32_bf16).
// B (t, transposed+bf16) staged in LDS for full K once (one barrier total).
// A loaded DIRECT TO REGISTERS from the tiled Wt: each fragment load is
// 1024 consecutive bytes per wave (fully coalesced), 1-deep prefetch fenced
// with sched_barrier. No A-LDS -> 50KB LDS -> 2 blocks/CU.
// ---------------------------------------------------------------------------
__global__ __launch_bounds__(512, 4) void gemm_kernel(
    const unsigned short* __restrict__ Wt, const float* __restrict__ t,
    const int* __restrict__ perm, const int* __restrict__ hist,
    float* __restrict__ out) {
    // bijective XCD-aware swizzle over [0, MAXCH)
    int orig = blockIdx.x;
    const int qq = MAXCH >> 3, r8 = MAXCH & 7;
    int xcd = orig & 7, off = orig >> 3;
    int chunk = (xcd < r8 ? xcd * (qq + 1) : r8 * (qq + 1) + (xcd - r8) * qq) + off;

    // chunk table recomputed from the 10-entry histogram (scalar, no arrays)
    int z = -1, ns = 0, nn = 0;
    {
        int cum = 0, cc = 0;
#pragma unroll
        for (int zz = 0; zz < Z_N; ++zz) {
            int hz = hist[zz];
            int czz = (hz + NPC - 1) / NPC;
            if (z < 0 && chunk < cc + czz) {
                z = zz;
                int j = (chunk - cc) * NPC;
                ns = cum + j;
                nn = (hz - j < NPC) ? (hz - j) : NPC;
            }
            cum += hz; cc += czz;
        }
        if (chunk >= cc) return;
    }

    __shared__ __align__(16) char B_s[BN * BSTRIDE];   // 49,920 B
    __shared__ int col_ob[BN];

    int tid = threadIdx.x;
    int lane = tid & 63, wid = tid >> 6;
    int lrow = lane & 15, g = lane >> 4;
    int wrow = wid * 64;

    // ---- stage B: fp32 t -> bf16, transposed to [col=(n,d)][k] ----
    {
        int n = tid >> 5, grp = tid & 31;       // node slot, k-16-group
        int node = (n < nn) ? perm[ns + n] : -1;
        float f[48];
        if (node >= 0) {
            const float4* tp = reinterpret_cast<const float4*>(
                t + (size_t)node * (IN_D * M_N)) + grp * 12;
#pragma unroll
            for (int j = 0; j < 12; ++j) {
                float4 v = tp[j];
                f[4 * j]     = v.x; f[4 * j + 1] = v.y;
                f[4 * j + 2] = v.z; f[4 * j + 3] = v.w;
            }
        } else {
#pragma unroll
            for (int j = 0; j < 48; ++j) f[j] = 0.f;
        }
#pragma unroll
        for (int d = 0; d < 3; ++d) {
#pragma unroll
            for (int j = 0; j < 2; ++j) {
                short8v v;
#pragma unroll
                for (int i = 0; i < 8; ++i)
                    v[i] = (short)f2bf(f[3 * (j * 8 + i) + d]);
                *reinterpret_cast<short8v*>(
                    B_s + (n * 3 + d) * BSTRIDE + (grp * 2 + j) * 16) = v;
            }
        }
        if (tid < BN) {
            int nl = tid / 3, d = tid - nl * 3;
            col_ob[tid] = (nl < nn) ? perm[ns + nl] * (OUT_D * M_N) + d : -1;
        }
    }
    __syncthreads();

    float4v acc[4][3];
#pragma unroll
    for (int mi = 0; mi < 4; ++mi)
#pragma unroll
        for (int ni = 0; ni < 3; ++ni) acc[mi][ni] = (float4v){0.f, 0.f, 0.f, 0.f};

    const char* bp0 = B_s + lrow * BSTRIDE + g * 16;
    // lane's A base in tiled Wt: row = wrow+lrow, chunk g (8 ushorts)
    const unsigned short* aw = Wt + (size_t)z * 262144
                               + (size_t)(wrow + lrow) * 32 + (size_t)g * 8;

    short8v aC[4], aN[4];
#pragma unroll
    for (int mi = 0; mi < 4; ++mi)
        aC[mi] = *reinterpret_cast<const short8v*>(aw + mi * 512);

// one K-step: prefetch kt+1 A-frags (coalesced 1KB/instr), fence, 12 MFMAs
#define KSTEP(KT, CUR, NXT)                                                     \
    {                                                                           \
        if ((KT) + 1 < 16) {                                                    \
            _Pragma("unroll")                                                   \
            for (int mi = 0; mi < 4; ++mi)                                      \
                NXT[mi] = *reinterpret_cast<const short8v*>(                    \
                    aw + ((KT) + 1) * 16384 + mi * 512);                        \
        }                                                                       \
        __builtin_amdgcn_sched_barrier(0);                                      \
        short8v b0 = *reinterpret_cast<const short8v*>(bp0 + 0 * 16 * BSTRIDE + (KT) * 64); \
        short8v b1 = *reinterpret_cast<const short8v*>(bp0 + 1 * 16 * BSTRIDE + (KT) * 64); \
        short8v b2 = *reinterpret_cast<const short8v*>(bp0 + 2 * 16 * BSTRIDE + (KT) * 64); \
        acc[0][0] = __builtin_amdgcn_mfma_f32_16x16x32_bf16(CUR[0], b0, acc[0][0], 0, 0, 0); \
        acc[0][1] = __builtin_amdgcn_mfma_f32_16x16x32_bf16(CUR[0], b1, acc[0][1], 0, 0, 0); \
        acc[0][2] = __builtin_amdgcn_mfma_f32_16x16x32_bf16(CUR[0], b2, acc[0][2], 0, 0, 0); \
        acc[1][0] = __builtin_amdgcn_mfma_f32_16x16x32_bf16(CUR[1], b0, acc[1][0], 0, 0, 0); \
        acc[1][1] = __builtin_amdgcn_mfma_f32_16x16x32_bf16(CUR[1], b1, acc[1][1], 0, 0, 0); \
        acc[1][2] = __builtin_amdgcn_mfma_f32_16x16x32_bf16(CUR[1], b2, acc[1][2], 0, 0, 0); \
        acc[2][0] = __builtin_amdgcn_mfma_f32_16x16x32_bf16(CUR[2], b0, acc[2][0], 0, 0, 0); \
        acc[2][1] = __builtin_amdgcn_mfma_f32_16x16x32_bf16(CUR[2], b1, acc[2][1], 0, 0, 0); \
        acc[2][2] = __builtin_amdgcn_mfma_f32_16x16x32_bf16(CUR[2], b2, acc[2][2], 0, 0, 0); \
        acc[3][0] = __builtin_amdgcn_mfma_f32_16x16x32_bf16(CUR[3], b0, acc[3][0], 0, 0, 0); \
        acc[3][1] = __builtin_amdgcn_mfma_f32_16x16x32_bf16(CUR[3], b1, acc[3][1], 0, 0, 0); \
        acc[3][2] = __builtin_amdgcn_mfma_f32_16x16x32_bf16(CUR[3], b2, acc[3][2], 0, 0, 0); \
        __builtin_amdgcn_sched_barrier(0);                                      \
    }

    KSTEP(0, aC, aN)  KSTEP(1, aN, aC)  KSTEP(2, aC, aN)  KSTEP(3, aN, aC)
    KSTEP(4, aC, aN)  KSTEP(5, aN, aC)  KSTEP(6, aC, aN)  KSTEP(7, aN, aC)
    KSTEP(8, aC, aN)  KSTEP(9, aN, aC)  KSTEP(10, aC, aN) KSTEP(11, aN, aC)
    KSTEP(12, aC, aN) KSTEP(13, aN, aC) KSTEP(14, aC, aN) KSTEP(15, aN, aC)
#undef KSTEP

    // C/D layout: col = lane&15 (B col), row = g*4+e within fragment (m89)
    int base_row = wrow + g * 4;
#pragma unroll
    for (int ni = 0; ni < 3; ++ni) {
        int ob = col_ob[ni * 16 + lrow];
        if (ob < 0) continue;
#pragma unroll
        for (int mi = 0; mi < 4; ++mi) {
            int orow = base_row + mi * 16;
#pragma unroll
            for (int e = 0; e < 4; ++e)
                out[ob + (size_t)(orow + e) * M_N] = acc[mi][ni][e];
        }
    }
}

// ---------------------------------------------------------------------------
// Fallback (round-1 path) if ws is too small — row-major Wbf layout
// ---------------------------------------------------------------------------
__global__ __launch_bounds__(256) void merge_w_kernel(
    const float* __restrict__ weights, const float* __restrict__ lora_A,
    const float* __restrict__ lora_B, unsigned short* __restrict__ Wbf) {
    int zo = blockIdx.x;
    int z = zo >> 9;
    int o = zo & (OUT_D - 1);
    int tid = threadIdx.x;
    float lb[R_N];
    const float* bp = lora_B + ((size_t)z * OUT_D + o) * R_N;
#pragma unroll
    for (int r = 0; r < R_N; ++r) lb[r] = bp[r];
    const float* ap = lora_A + (size_t)z * R_N * IN_D;
    const float* wp = weights + ((size_t)z * OUT_D + o) * IN_D;
    unsigned short* op = Wbf + ((size_t)z * OUT_D + o) * IN_D;
    for (int i = tid; i < IN_D; i += 256) {
        float acc = wp[i];
#pragma unroll
        for (int r = 0; r < R_N; ++r) acc += ap[r * IN_D + i] * lb[r];
        op[i] = f2bf(acc * ALPHA);
    }
}

__global__ __launch_bounds__(256) void apply_kernel(
    const float* __restrict__ t, const float* __restrict__ attrs,
    const unsigned short* __restrict__ Wbf, float* __restrict__ out) {
    int b = blockIdx.x;
    int tid = threadIdx.x;
    const float* ab = attrs + (size_t)b * Z_N;
    int z = 0;
#pragma unroll
    for (int zz = 1; zz < Z_N; ++zz)
        if (ab[zz] > 0.5f) z = zz;
    __shared__ __align__(16) float t_s[IN_D * M_N];
    const float* tb = t + (size_t)b * (IN_D * M_N);
    for (int k = tid; k < IN_D * M_N; k += 256) t_s[k] = tb[k];
    __syncthreads();
    const unsigned short* w0 = Wbf + ((size_t)z * OUT_D + tid) * IN_D;
    const unsigned short* w1 = w0 + 256 * IN_D;
    float acc0[M_N] = {0.f, 0.f, 0.f};
    float acc1[M_N] = {0.f, 0.f, 0.f};
    for (int c = 0; c < IN_D; c += 8) {
        uint4 u0 = *reinterpret_cast<const uint4*>(w0 + c);
        uint4 u1 = *reinterpret_cast<const uint4*>(w1 + c);
        float wf0[8], wf1[8];
        unsigned int a0[4] = {u0.x, u0.y, u0.z, u0.w};
        unsigned int a1[4] = {u1.x, u1.y, u1.z, u1.w};
#pragma unroll
        for (int q = 0; q < 4; ++q) {
            wf0[2 * q] = bfbits_lo(a0[q]); wf0[2 * q + 1] = bfbits_hi(a0[q]);
            wf1[2 * q] = bfbits_lo(a1[q]); wf1[2 * q + 1] = bfbits_hi(a1[q]);
        }
        float tf[24];
        const float4* tv = reinterpret_cast<const float4*>(t_s + c * M_N);
#pragma unroll
        for (int q = 0; q < 6; ++q) {
            float4 v = tv[q];
            tf[4 * q] = v.x; tf[4 * q + 1] = v.y; tf[4 * q + 2] = v.z; tf[4 * q + 3] = v.w;
        }
#pragma unroll
        for (int cc = 0; cc < 8; ++cc)
#pragma unroll
            for (int d = 0; d < M_N; ++d) {
                acc0[d] += wf0[cc] * tf[cc * M_N + d];
                acc1[d] += wf1[cc] * tf[cc * M_N + d];
            }
    }
    float* ob = out + (size_t)b * (OUT_D * M_N);
#pragma unroll
    for (int d = 0; d < M_N; ++d) ob[tid * M_N + d] = acc0[d];
#pragma unroll
    for (int d = 0; d < M_N; ++d) ob[(tid + 256) * M_N + d] = acc1[d];
}

extern "C" void kernel_launch(void* const* d_in, const int* in_sizes, int n_in,
                              void* d_out, int out_size, void* d_ws, size_t ws_size,
                              hipStream_t stream) {
    const float* t       = (const float*)d_in[0];
    const float* attrs   = (const float*)d_in[1];
    const float* weights = (const float*)d_in[2];
    const float* lora_A  = (const float*)d_in[3];
    const float* lora_B  = (const float*)d_in[4];
    float* out = (float*)d_out;
    char* ws = (char*)d_ws;

    if (ws_size >= WS_NEED) {
        unsigned short* Wt = (unsigned short*)(ws + OFF_WT);
        int* perm = (int*)(ws + OFF_PERM);
        int* zarr = (int*)(ws + OFF_ZARR);
        int* hist = (int*)(ws + OFF_HIST);
        int* cnt  = (int*)(ws + OFF_CNT);

        hipMemsetAsync(hist, 0, SZ_HIST + SZ_CNT, stream);
        prep_kernel<<<MERGE_BLOCKS + ZHIST_BLOCKS, 256, 0, stream>>>(
            weights, lora_A, lora_B, attrs, Wt, zarr, hist);
        scatter_kernel<<<ZHIST_BLOCKS, 256, 0, stream>>>(zarr, hist, cnt, perm);
        gemm_kernel<<<MAXCH, 512, 0, stream>>>(Wt, t, perm, hist, out);
    } else if (ws_size >= SZ_WT) {
        unsigned short* Wbf = (unsigned short*)(ws + OFF_WT);
        merge_w_kernel<<<Z_N * OUT_D, 256, 0, stream>>>(weights, lora_A, lora_B, Wbf);
        apply_kernel<<<B_N, 256, 0, stream>>>(t, attrs, Wbf, out);
    }
}